// Round 5
// baseline (2007.939 us; speedup 1.0000x reference)
//
#include <hip/hip_runtime.h>
#include <hip/hip_bf16.h>

typedef __hip_bfloat16 bf16;

__device__ __forceinline__ float b2f(bf16 v) { return __bfloat162float(v); }
__device__ __forceinline__ bf16  f2b(float v) { return __float2bfloat16(v); }

// dtype-flexible input load: F32=1 -> float*, F32=0 -> bf16*
template<int F32>
__device__ __forceinline__ float ldin(const void* p, size_t i) {
  if (F32) return ((const float*)p)[i];
  return b2f(((const bf16*)p)[i]);
}

// ---------------------------------------------------------------------------
// dtype detector: bf16 N(0,1) never has exponent >= 0x90; fp32-as-u16 low
// halves are ~uniform -> ~44% exceed it. flag=1 means fp32.
// (Round-4 FETCH_SIZE ~= fp32 image bytes confirms this fires flag=1.)
// ---------------------------------------------------------------------------
__global__ void k_detect(const unsigned short* __restrict__ u, int* __restrict__ flag)
{
  if (threadIdx.x == 0 && blockIdx.x == 0) {
    int nbad = 0;
    for (int i = 0; i < 256; i++) {
      unsigned e = (u[i] >> 7) & 0xFFu;
      nbad += (e >= 0x90u) ? 1 : 0;
    }
    flag[0] = (nbad > 8) ? 1 : 0;
  }
}

// ---------------------------------------------------------------------------
// FUSED conv1+conv2. Block: 16x16 conv2 out px, 16 oc (og half); 1 px x 16 oc
// per thread. conv1 tile (34x34, 8-ch slices) in LDS; width 48 => 2-row pr
// stride = 48 dwords = 16 mod 32 banks -> exactly 2 lanes/bank (free).
// grid: x = col tile(16), y = (row tile(16)<<1)|og, z = net -> 1024 blocks,
// ~38 KB LDS -> 4 blocks/CU, launch_bounds(256,4) -> 16 waves/CU.
// ---------------------------------------------------------------------------
struct SmConv12 {
  bf16  c1s[8][34][48];   // 26,112 B
  float w1a[64][27];      //  6,912 B
  float b1a[64];          //    256 B
  float w2s[72][16];      //  4,608 B
  float b2s[16];          //     64 B
};

template<int F32>
__device__ __forceinline__ void conv12_impl(
    const void* __restrict__ IN, const void* __restrict__ W1,
    const void* __restrict__ B1, const void* __restrict__ W2,
    const void* __restrict__ B2, bf16* __restrict__ OUT,
    int R0, int C0, int og, SmConv12& sm)
{
  const int tid = threadIdx.x;
  // one-time staging: all conv1 weights/bias, conv2 bias
  for (int i = tid; i < 1728; i += 256) {          // 64*27
    int ch = i / 27, k = i - ch * 27;
    sm.w1a[ch][k] = ldin<F32>(W1, (size_t)ch * 27 + k);
  }
  if (tid < 64) sm.b1a[tid] = ldin<F32>(B1, tid);
  if (tid < 16) sm.b2s[tid] = ldin<F32>(B2, og * 16 + tid);
  __syncthreads();

  const int pr = tid >> 4, pc = tid & 15;          // out px (R0+pr, C0+pc)
  float acc[16];
  #pragma unroll
  for (int j = 0; j < 16; j++) acc[j] = sm.b2s[j];

  for (int ss = 0; ss < 8; ss++) {                 // conv1 channel slices of 8
    if (ss) __syncthreads();                       // prev phase B done

    // conv2 weights for this slice: w2s[icl*9+tap][ocl]
    for (int i = tid; i < 1152; i += 256) {        // 72*16
      int ocl = i & 15, kk = i >> 4;
      sm.w2s[kk][ocl] = ldin<F32>(W2,
          (size_t)(og * 16 + ocl) * 576 + (size_t)ss * 72 + kk);
    }

    // phase A: conv1 slice into LDS (rows lr: gr = 2*R0-1+lr; OOB -> zero pad)
    for (int i = tid; i < 1156; i += 256) {        // 34*34
      const int lr = i / 34, lc = i - lr * 34;
      const int gr = 2 * R0 - 1 + lr;
      const int gc = 2 * C0 - 1 + lc;
      if ((unsigned)gr < 512u && (unsigned)gc < 512u) {
        float a1[8];
        #pragma unroll
        for (int ch = 0; ch < 8; ch++) a1[ch] = sm.b1a[ss * 8 + ch];
        #pragma unroll
        for (int icc = 0; icc < 3; icc++) {
          const size_t icb = (size_t)icc * 1048576;
          #pragma unroll
          for (int ky = 0; ky < 3; ky++) {
            const int iy = 2 * gr - 1 + ky;
            const bool oky = (unsigned)iy < 1024u;
            #pragma unroll
            for (int kx = 0; kx < 3; kx++) {
              const int ix = 2 * gc - 1 + kx;
              const float v = (oky && (unsigned)ix < 1024u)
                            ? ldin<F32>(IN, icb + (size_t)iy * 1024 + ix) : 0.f;
              const int k = icc * 9 + ky * 3 + kx;
              #pragma unroll
              for (int ch = 0; ch < 8; ch++)
                a1[ch] += sm.w1a[ss * 8 + ch][k] * v;
            }
          }
        }
        #pragma unroll
        for (int ch = 0; ch < 8; ch++)
          sm.c1s[ch][lr][lc] = f2b(fmaxf(a1[ch], 0.f));   // ReLU
      } else {
        #pragma unroll
        for (int ch = 0; ch < 8; ch++) sm.c1s[ch][lr][lc] = f2b(0.f);
      }
    }
    __syncthreads();

    // phase B: conv2 accumulate from LDS slice
    #pragma unroll
    for (int icl = 0; icl < 8; icl++) {
      float iv[3][3];
      #pragma unroll
      for (int ky = 0; ky < 3; ky++)
        #pragma unroll
        for (int kx = 0; kx < 3; kx++)
          iv[ky][kx] = b2f(sm.c1s[icl][2 * pr + ky][2 * pc + kx]);
      #pragma unroll
      for (int ky = 0; ky < 3; ky++) {
        #pragma unroll
        for (int kx = 0; kx < 3; kx++) {
          const int kk = icl * 9 + ky * 3 + kx;
          const float v = iv[ky][kx];
          #pragma unroll
          for (int j4 = 0; j4 < 4; j4++) {
            float4 w4 = *(const float4*)&sm.w2s[kk][j4 * 4];
            acc[j4*4+0] += w4.x * v; acc[j4*4+1] += w4.y * v;
            acc[j4*4+2] += w4.z * v; acc[j4*4+3] += w4.w * v;
          }
        }
      }
    }
  }

  const size_t sp = (size_t)(R0 + pr) * 256 + (C0 + pc);
  #pragma unroll
  for (int j = 0; j < 16; j++)
    OUT[(size_t)(og * 16 + j) * 65536 + sp] = f2b(fmaxf(acc[j], 0.f));  // ReLU
}

__global__ __launch_bounds__(256, 4) void k_conv12(
    const void* __restrict__ in0, const void* __restrict__ in1,
    const void* __restrict__ w1_0, const void* __restrict__ b1_0,
    const void* __restrict__ w1_1, const void* __restrict__ b1_1,
    const void* __restrict__ w2_0, const void* __restrict__ b2_0,
    const void* __restrict__ w2_1, const void* __restrict__ b2_1,
    bf16* __restrict__ c2o, const int* __restrict__ flag)
{
  __shared__ SmConv12 sm;
  const int n  = blockIdx.z;
  const int og = blockIdx.y & 1;
  const int ty = blockIdx.y >> 1;                  // 0..15
  const int R0 = ty * 16, C0 = blockIdx.x * 16;
  const void* IN = n ? in1  : in0;                 // n=0 style/snet, 1 content/cnet
  const void* W1 = n ? w1_1 : w1_0;
  const void* B1 = n ? b1_1 : b1_0;
  const void* W2 = n ? w2_1 : w2_0;
  const void* B2 = n ? b2_1 : b2_0;
  bf16* OUT = c2o + (size_t)n * 2097152;
  if (flag[0]) conv12_impl<1>(IN, W1, B1, W2, B2, OUT, R0, C0, og, sm);
  else         conv12_impl<0>(IN, W1, B1, W2, B2, OUT, R0, C0, og, sm);
}

// ---------------------------------------------------------------------------
// conv3: 32->16 ch, 256^2 -> 128^2, s2 p1, NO relu, fp32 out [2][16][16384]
// og split (8 oc/thread) -> grid (64, 2, 2) = 256 blocks
// ---------------------------------------------------------------------------
struct SmConv3 { float wl[288][8]; float bl[8]; };

template<int F32>
__device__ __forceinline__ void conv3_impl(
    const bf16* __restrict__ IN, const void* __restrict__ W,
    const void* __restrict__ B, float* __restrict__ O, int og, SmConv3& sm)
{
  const int tid = threadIdx.x;
  for (int i = tid; i < 2304; i += 256) {          // 288*8
    int ocl = i & 7, kk = i >> 3;
    sm.wl[kk][ocl] = ldin<F32>(W, (size_t)(og * 8 + ocl) * 288 + kk);
  }
  if (tid < 8) sm.bl[tid] = ldin<F32>(B, og * 8 + tid);
  __syncthreads();
  const int s = blockIdx.x * 256 + tid;            // 0..16383
  const int oy = s >> 7, ox = s & 127;
  float acc[8];
  #pragma unroll
  for (int j = 0; j < 8; j++) acc[j] = sm.bl[j];
  for (int ic = 0; ic < 32; ic++) {
    const bf16* __restrict__ Ic = IN + (size_t)ic * 65536;
    #pragma unroll
    for (int ky = 0; ky < 3; ky++) {
      int iy = 2 * oy + ky - 1;
      bool oky = (unsigned)iy < 256u;
      #pragma unroll
      for (int kx = 0; kx < 3; kx++) {
        int ix = 2 * ox + kx - 1;
        float v = (oky && (unsigned)ix < 256u) ? b2f(Ic[(long)iy * 256 + ix]) : 0.f;
        const int kk = ic * 9 + ky * 3 + kx;
        float4 wA = *(const float4*)&sm.wl[kk][0];
        float4 wB = *(const float4*)&sm.wl[kk][4];
        acc[0] += wA.x * v; acc[1] += wA.y * v; acc[2] += wA.z * v; acc[3] += wA.w * v;
        acc[4] += wB.x * v; acc[5] += wB.y * v; acc[6] += wB.z * v; acc[7] += wB.w * v;
      }
    }
  }
  #pragma unroll
  for (int j = 0; j < 8; j++) O[(size_t)(og * 8 + j) * 16384 + s] = acc[j];
}

__global__ __launch_bounds__(256) void k_conv3(
    const bf16* __restrict__ in,
    const void* __restrict__ w0, const void* __restrict__ bi0,
    const void* __restrict__ w1, const void* __restrict__ bi1,
    float* __restrict__ out, const int* __restrict__ flag)
{
  __shared__ SmConv3 sm;
  const int n = blockIdx.z, og = blockIdx.y;
  const bf16* IN = in + (size_t)n * 32 * 65536;
  const void* W = n ? w1 : w0;
  const void* B = n ? bi1 : bi0;
  float* O = out + (size_t)n * 16 * 16384;
  if (flag[0]) conv3_impl<1>(IN, W, B, O, og, sm);
  else         conv3_impl<0>(IN, W, B, O, og, sm);
}

// ---------------------------------------------------------------------------
// gather + maxpool (fp32 scratch, dtype-independent)
// ---------------------------------------------------------------------------
__global__ __launch_bounds__(256) void k_pool(
    const float* __restrict__ feat, const int* __restrict__ fgs,
    const int* __restrict__ fgc, float* __restrict__ pooled)
{
  int t = blockIdx.x * 256 + threadIdx.x;   // 0..8191
  int n = t >> 12, rem = t & 4095;
  int c = rem >> 8, p = rem & 255;
  const int* __restrict__ m = n ? fgc : fgs;
  const float* __restrict__ F = feat + (size_t)n * 16 * 16384 + (size_t)c * 16384;
  float mx = -3.4e38f;
  #pragma unroll 4
  for (int j = 0; j < 32; j++) mx = fmaxf(mx, F[m[p * 32 + j]]);
  pooled[(size_t)n * 4096 + rem] = mx;
}

// ---------------------------------------------------------------------------
// FC: mats[n][i] = fcb[i] + sum_j pooled[n][j]*fcw[i][j]
// ---------------------------------------------------------------------------
template<int F32>
__device__ __forceinline__ void fc_impl(
    const float* __restrict__ P, const void* __restrict__ W,
    const void* __restrict__ B, float* __restrict__ dst, int i, float* red)
{
  const int tid = threadIdx.x;
  float p = 0.f;
  for (int j = tid; j < 4096; j += 256) p += P[j] * ldin<F32>(W, (size_t)i * 4096 + j);
  red[tid] = p;
  __syncthreads();
  for (int off = 128; off > 0; off >>= 1) {
    if (tid < off) red[tid] += red[tid + off];
    __syncthreads();
  }
  if (tid == 0) *dst = red[0] + ldin<F32>(B, i);
}

__global__ __launch_bounds__(256) void k_fc(
    const float* __restrict__ pooled,
    const void* __restrict__ w0, const void* __restrict__ bb0,
    const void* __restrict__ w1, const void* __restrict__ bb1,
    float* __restrict__ mats, const int* __restrict__ flag)
{
  __shared__ float red[256];
  const int n = blockIdx.z, i = blockIdx.x;
  const void* W = n ? w1 : w0;
  const void* B = n ? bb1 : bb0;
  const float* P = pooled + (size_t)n * 4096;
  float* dst = &mats[(size_t)n * 4096 + i];
  if (flag[0]) fc_impl<1>(P, W, B, dst, i, red);
  else         fc_impl<0>(P, W, B, dst, i, red);
}

// T = sMat @ cMat
__global__ __launch_bounds__(256) void k_tmat(
    const float* __restrict__ mats, float* __restrict__ T)
{
  int t = blockIdx.x * 256 + threadIdx.x;   // 0..4095
  int i = t >> 6, j = t & 63;
  const float* __restrict__ S = mats;
  const float* __restrict__ C = mats + 4096;
  float a = 0.f;
  #pragma unroll 8
  for (int k = 0; k < 64; k++) a += S[i * 64 + k] * C[k * 64 + j];
  T[t] = a;
}

// ---------------------------------------------------------------------------
// compress: ccf[o][s] = cb[o] + sum_c cw[o][c]*cF[c][s]  (fp32 out)
// ---------------------------------------------------------------------------
struct SmCompress { float wl[512][8]; float bl[8]; };

template<int F32>
__device__ __forceinline__ void compress_impl(
    const void* __restrict__ cF, const void* __restrict__ cw,
    const void* __restrict__ cb, float* __restrict__ ccf, int og, SmCompress& sm)
{
  const int tid = threadIdx.x;
  for (int i = tid; i < 4096; i += 256) {
    int ol = i & 7, c = i >> 3;
    sm.wl[c][ol] = ldin<F32>(cw, (size_t)(og * 8 + ol) * 512 + c);
  }
  if (tid < 8) sm.bl[tid] = ldin<F32>(cb, og * 8 + tid);
  __syncthreads();
  const int s = blockIdx.x * 256 + tid;
  float acc[8];
  #pragma unroll
  for (int j = 0; j < 8; j++) acc[j] = sm.bl[j];
  for (int c = 0; c < 512; c++) {
    float v = ldin<F32>(cF, (size_t)c * 16384 + s);
    float4 wA = *(const float4*)&sm.wl[c][0];
    float4 wB = *(const float4*)&sm.wl[c][4];
    acc[0] += wA.x * v; acc[1] += wA.y * v; acc[2] += wA.z * v; acc[3] += wA.w * v;
    acc[4] += wB.x * v; acc[5] += wB.y * v; acc[6] += wB.z * v; acc[7] += wB.w * v;
  }
  #pragma unroll
  for (int j = 0; j < 8; j++) ccf[(size_t)(og * 8 + j) * 16384 + s] = acc[j];
}

__global__ __launch_bounds__(256) void k_compress(
    const void* __restrict__ cF, const void* __restrict__ cw,
    const void* __restrict__ cb, float* __restrict__ ccf,
    const int* __restrict__ flag)
{
  __shared__ SmCompress sm;
  const int og = blockIdx.y;
  if (flag[0]) compress_impl<1>(cF, cw, cb, ccf, og, sm);
  else         compress_impl<0>(cF, cw, cb, ccf, og, sm);
}

__global__ __launch_bounds__(256) void k_mean(
    const float* __restrict__ ccf, float* __restrict__ mean)
{
  const int o = blockIdx.x;
  const int tid = threadIdx.x;
  __shared__ float red[256];
  const float* __restrict__ R = ccf + (size_t)o * 16384;
  float p = 0.f;
  for (int s = tid; s < 16384; s += 256) p += R[s];
  red[tid] = p;
  __syncthreads();
  for (int off = 128; off > 0; off >>= 1) {
    if (tid < off) red[tid] += red[tid + off];
    __syncthreads();
  }
  if (tid == 0) mean[o] = red[0] * (1.f / 16384.f);
}

__global__ __launch_bounds__(256) void k_scatter(
    const int* __restrict__ fgc, int* __restrict__ maskf)
{
  int t = blockIdx.x * 256 + threadIdx.x;   // 0..8191
  maskf[fgc[t]] = 1;
}

// ---------------------------------------------------------------------------
// transform -> tf bf16 (scratch-only, dtype-independent)
// ---------------------------------------------------------------------------
__global__ __launch_bounds__(256) void k_transform(
    const float* __restrict__ ccf, const float* __restrict__ Tm,
    const float* __restrict__ mean, const int* __restrict__ maskf,
    bf16* __restrict__ tf)
{
  const int og = blockIdx.y;
  __shared__ __align__(16) float Tl[16][64];
  __shared__ float ml[64];
  const int tid = threadIdx.x;
  for (int i = tid; i < 1024; i += 256) {
    int ol = i >> 6, op = i & 63;
    Tl[ol][op] = Tm[(size_t)(og * 16 + ol) * 64 + op];
  }
  if (tid < 64) ml[tid] = mean[tid];
  __syncthreads();
  const int s = blockIdx.x * 256 + tid;
  const bool msk = maskf[s] != 0;
  float col[64];
  #pragma unroll
  for (int op = 0; op < 64; op++) col[op] = ccf[(size_t)op * 16384 + s] - ml[op];
  #pragma unroll
  for (int ol = 0; ol < 16; ol++) {
    float a = 0.f;
    #pragma unroll
    for (int op4 = 0; op4 < 16; op4++) {
      float4 t4 = *(const float4*)&Tl[ol][op4 * 4];
      a += t4.x * col[op4*4+0] + t4.y * col[op4*4+1]
         + t4.z * col[op4*4+2] + t4.w * col[op4*4+3];
    }
    float un = ccf[(size_t)(og * 16 + ol) * 16384 + s] - ml[og * 16 + ol];
    tf[(size_t)(og * 16 + ol) * 16384 + s] = f2b(msk ? a : un);
  }
}

// ---------------------------------------------------------------------------
// unzip: out[u][s] = ub[u] + sum_o uw[u][o]*tf[o][s]  -> out dtype per flag
// ---------------------------------------------------------------------------
struct SmUnzip { float wl[64][32]; float bl[32]; };

template<int F32>
__device__ __forceinline__ void unzip_impl(
    const bf16* __restrict__ tf, const void* __restrict__ uw,
    const void* __restrict__ ub, void* __restrict__ outp, int ug, SmUnzip& sm)
{
  const int tid = threadIdx.x;
  for (int i = tid; i < 2048; i += 256) {
    int ul = i & 31, o = i >> 5;
    sm.wl[o][ul] = ldin<F32>(uw, (size_t)(ug * 32 + ul) * 64 + o);
  }
  if (tid < 32) sm.bl[tid] = ldin<F32>(ub, ug * 32 + tid);
  __syncthreads();
  const int s = blockIdx.x * 256 + tid;
  float acc[32];
  #pragma unroll
  for (int j = 0; j < 32; j++) acc[j] = sm.bl[j];
  #pragma unroll 4
  for (int o = 0; o < 64; o++) {
    float v = b2f(tf[(size_t)o * 16384 + s]);
    #pragma unroll
    for (int j4 = 0; j4 < 8; j4++) {
      float4 w4 = *(const float4*)&sm.wl[o][j4 * 4];
      acc[j4*4+0] += w4.x * v; acc[j4*4+1] += w4.y * v;
      acc[j4*4+2] += w4.z * v; acc[j4*4+3] += w4.w * v;
    }
  }
  #pragma unroll
  for (int j = 0; j < 32; j++) {
    size_t idx = (size_t)(ug * 32 + j) * 16384 + s;
    if (F32) ((float*)outp)[idx] = acc[j];
    else     ((bf16*)outp)[idx]  = f2b(acc[j]);
  }
}

__global__ __launch_bounds__(256) void k_unzip(
    const bf16* __restrict__ tf, const void* __restrict__ uw,
    const void* __restrict__ ub, void* __restrict__ outp,
    const int* __restrict__ flag)
{
  __shared__ SmUnzip sm;
  const int ug = blockIdx.y;
  if (flag[0]) unzip_impl<1>(tf, uw, ub, outp, ug, sm);
  else         unzip_impl<0>(tf, uw, ub, outp, ug, sm);
}

// ---------------------------------------------------------------------------
extern "C" void kernel_launch(void* const* d_in, const int* in_sizes, int n_in,
                              void* d_out, int out_size, void* d_ws, size_t ws_size,
                              hipStream_t stream)
{
  const void* cF      = d_in[0];
  // d_in[1] = sF (unused by reference)
  const void* content = d_in[2];
  const void* style   = d_in[3];
  const void* s_c1w = d_in[4];  const void* s_c1b = d_in[5];
  const void* s_c2w = d_in[6];  const void* s_c2b = d_in[7];
  const void* s_c3w = d_in[8];  const void* s_c3b = d_in[9];
  const void* s_fcw = d_in[10]; const void* s_fcb = d_in[11];
  const void* c_c1w = d_in[12]; const void* c_c1b = d_in[13];
  const void* c_c2w = d_in[14]; const void* c_c2b = d_in[15];
  const void* c_c3w = d_in[16]; const void* c_c3b = d_in[17];
  const void* c_fcw = d_in[18]; const void* c_fcb = d_in[19];
  const void* cw = d_in[20];    const void* cb = d_in[21];
  const void* uw = d_in[22];    const void* ub = d_in[23];
  const int* fgc = (const int*)d_in[24];
  const int* fgs = (const int*)d_in[25];
  (void)in_sizes; (void)n_in; (void)out_size; (void)ws_size;

  // scratch inside d_out (14.83 MB; d_out >= 16.77 MB); fully rewritten by
  // the final k_unzip which reads nothing from d_out.
  char* ob = (char*)d_out;
  bf16*  c2o    = (bf16*)(ob + 0);           // [2][32][65536] bf16  8,388,608 B
  float* c3o    = (float*)(ob + 8388608);    // [2][16][16384] f32   2,097,152 B
  float* ccf    = (float*)(ob + 10485760);   // [64][16384]  f32     4,194,304 B
  float* pooled = (float*)(ob + 14680064);   // [2][4096]               32,768 B
  float* mats   = (float*)(ob + 14712832);   // [2][4096]               32,768 B
  float* T      = (float*)(ob + 14745600);   // [64][64]                16,384 B
  float* mean   = (float*)(ob + 14761984);   // [64]+pad                 1,024 B
  int*   maskf  = (int*)(ob + 14763008);     // [16384]                 65,536 B
  int*   flag   = (int*)(ob + 14828544);     // dtype flag                  16 B

  bf16* tf = (bf16*)d_ws;                    // [64][16384] bf16, 2,097,152 B

  k_detect<<<1, 64, 0, stream>>>((const unsigned short*)cF, flag);
  (void)hipMemsetAsync(maskf, 0, 16384 * sizeof(int), stream);
  k_scatter<<<32, 256, 0, stream>>>(fgc, maskf);

  // fused conv1+conv2: 1024 blocks
  k_conv12<<<dim3(16, 32, 2), 256, 0, stream>>>(
      style, content, s_c1w, s_c1b, c_c1w, c_c1b,
      s_c2w, s_c2b, c_c2w, c_c2b, c2o, flag);

  k_conv3<<<dim3(64, 2, 2), 256, 0, stream>>>(c2o, s_c3w, s_c3b, c_c3w, c_c3b, c3o, flag);
  k_pool<<<32, 256, 0, stream>>>(c3o, fgs, fgc, pooled);
  k_fc<<<dim3(4096, 1, 2), 256, 0, stream>>>(pooled, s_fcw, s_fcb, c_fcw, c_fcb, mats, flag);
  k_tmat<<<16, 256, 0, stream>>>(mats, T);

  k_compress<<<dim3(64, 8), 256, 0, stream>>>(cF, cw, cb, ccf, flag);
  k_mean<<<64, 256, 0, stream>>>(ccf, mean);
  k_transform<<<dim3(64, 4), 256, 0, stream>>>(ccf, T, mean, maskf, tf);
  k_unzip<<<dim3(64, 16), 256, 0, stream>>>(tf, uw, ub, d_out, flag);
}

// Round 6
// 861.440 us; speedup vs baseline: 2.3309x; 2.3309x over previous
//
#include <hip/hip_runtime.h>
#include <hip/hip_bf16.h>

typedef __hip_bfloat16 bf16;

__device__ __forceinline__ float b2f(bf16 v) { return __bfloat162float(v); }
__device__ __forceinline__ bf16  f2b(float v) { return __float2bfloat16(v); }

// dtype-flexible input load: F32=1 -> float*, F32=0 -> bf16*
template<int F32>
__device__ __forceinline__ float ldin(const void* p, size_t i) {
  if (F32) return ((const float*)p)[i];
  return b2f(((const bf16*)p)[i]);
}

// ---------------------------------------------------------------------------
// dtype detector: bf16 N(0,1) never has exponent >= 0x90; fp32-as-u16 low
// halves are ~uniform -> ~44% exceed it. flag=1 means fp32.
// (Round-4/5 FETCH_SIZE ~= fp32 image bytes confirms flag=1 on this harness.)
// ---------------------------------------------------------------------------
__global__ void k_detect(const unsigned short* __restrict__ u, int* __restrict__ flag)
{
  if (threadIdx.x == 0 && blockIdx.x == 0) {
    int nbad = 0;
    for (int i = 0; i < 256; i++) {
      unsigned e = (u[i] >> 7) & 0xFFu;
      nbad += (e >= 0x90u) ? 1 : 0;
    }
    flag[0] = (nbad > 8) ? 1 : 0;
  }
}

// ---------------------------------------------------------------------------
// FUSED conv1+conv2. Block: 16x16 conv2 out px, 16 oc (og half); 1 px x 16 oc
// per thread. conv1 tile (34x34, 8-ch slices) in LDS; padded width 48 ->
// phase-B 2-row stride = 48 dwords = 16 mod 32 banks -> 2 lanes/bank (free;
// verified round 5: SQ_LDS_BANK_CONFLICT = 0).
// grid: 16 x 32 x 2 = 1024 blocks, 38.4 KB LDS -> 4 blocks/CU by LDS.
// NO min-waves hint: round 5's (256,4) clamped VGPRs to 64 -> 6.6 GB spill
// traffic (FETCH 2.4 GB, WRITE 4.1 GB). Plain 256 gave 140 VGPR, no spill.
// ---------------------------------------------------------------------------
struct SmConv12 {
  bf16  c1s[8][34][48];   // 26,112 B
  float w1a[64][27];      //  6,912 B
  float b1a[64];          //    256 B
  float w2s[72][16];      //  4,608 B
  float b2s[16];          //     64 B
};

template<int F32>
__device__ __forceinline__ void conv12_impl(
    const void* __restrict__ IN, const void* __restrict__ W1,
    const void* __restrict__ B1, const void* __restrict__ W2,
    const void* __restrict__ B2, bf16* __restrict__ OUT,
    int R0, int C0, int og, SmConv12& sm)
{
  const int tid = threadIdx.x;
  // one-time staging: all conv1 weights/bias, conv2 bias
  for (int i = tid; i < 1728; i += 256) {          // 64*27
    int ch = i / 27, k = i - ch * 27;
    sm.w1a[ch][k] = ldin<F32>(W1, (size_t)ch * 27 + k);
  }
  if (tid < 64) sm.b1a[tid] = ldin<F32>(B1, tid);
  if (tid < 16) sm.b2s[tid] = ldin<F32>(B2, og * 16 + tid);
  __syncthreads();

  const int pr = tid >> 4, pc = tid & 15;          // out px (R0+pr, C0+pc)
  float acc[16];
  #pragma unroll
  for (int j = 0; j < 16; j++) acc[j] = sm.b2s[j];

  for (int ss = 0; ss < 8; ss++) {                 // conv1 channel slices of 8
    if (ss) __syncthreads();                       // prev phase B done

    // conv2 weights for this slice: w2s[icl*9+tap][ocl]
    for (int i = tid; i < 1152; i += 256) {        // 72*16
      int ocl = i & 15, kk = i >> 4;
      sm.w2s[kk][ocl] = ldin<F32>(W2,
          (size_t)(og * 16 + ocl) * 576 + (size_t)ss * 72 + kk);
    }

    // phase A: conv1 slice into LDS (gr = 2*R0-1+lr; OOB -> zero pad)
    for (int i = tid; i < 1156; i += 256) {        // 34*34
      const int lr = i / 34, lc = i - lr * 34;
      const int gr = 2 * R0 - 1 + lr;
      const int gc = 2 * C0 - 1 + lc;
      if ((unsigned)gr < 512u && (unsigned)gc < 512u) {
        float a1[8];
        #pragma unroll
        for (int ch = 0; ch < 8; ch++) a1[ch] = sm.b1a[ss * 8 + ch];
        #pragma unroll
        for (int icc = 0; icc < 3; icc++) {
          const size_t icb = (size_t)icc * 1048576;
          #pragma unroll
          for (int ky = 0; ky < 3; ky++) {
            const int iy = 2 * gr - 1 + ky;
            const bool oky = (unsigned)iy < 1024u;
            #pragma unroll
            for (int kx = 0; kx < 3; kx++) {
              const int ix = 2 * gc - 1 + kx;
              const float v = (oky && (unsigned)ix < 1024u)
                            ? ldin<F32>(IN, icb + (size_t)iy * 1024 + ix) : 0.f;
              const int k = icc * 9 + ky * 3 + kx;
              #pragma unroll
              for (int ch = 0; ch < 8; ch++)
                a1[ch] += sm.w1a[ss * 8 + ch][k] * v;
            }
          }
        }
        #pragma unroll
        for (int ch = 0; ch < 8; ch++)
          sm.c1s[ch][lr][lc] = f2b(fmaxf(a1[ch], 0.f));   // ReLU
      } else {
        #pragma unroll
        for (int ch = 0; ch < 8; ch++) sm.c1s[ch][lr][lc] = f2b(0.f);
      }
    }
    __syncthreads();

    // phase B: conv2 accumulate from LDS slice
    #pragma unroll
    for (int icl = 0; icl < 8; icl++) {
      float iv[3][3];
      #pragma unroll
      for (int ky = 0; ky < 3; ky++)
        #pragma unroll
        for (int kx = 0; kx < 3; kx++)
          iv[ky][kx] = b2f(sm.c1s[icl][2 * pr + ky][2 * pc + kx]);
      #pragma unroll
      for (int ky = 0; ky < 3; ky++) {
        #pragma unroll
        for (int kx = 0; kx < 3; kx++) {
          const int kk = icl * 9 + ky * 3 + kx;
          const float v = iv[ky][kx];
          #pragma unroll
          for (int j4 = 0; j4 < 4; j4++) {
            float4 w4 = *(const float4*)&sm.w2s[kk][j4 * 4];
            acc[j4*4+0] += w4.x * v; acc[j4*4+1] += w4.y * v;
            acc[j4*4+2] += w4.z * v; acc[j4*4+3] += w4.w * v;
          }
        }
      }
    }
  }

  const size_t sp = (size_t)(R0 + pr) * 256 + (C0 + pc);
  #pragma unroll
  for (int j = 0; j < 16; j++)
    OUT[(size_t)(og * 16 + j) * 65536 + sp] = f2b(fmaxf(acc[j], 0.f));  // ReLU
}

__global__ __launch_bounds__(256) void k_conv12(
    const void* __restrict__ in0, const void* __restrict__ in1,
    const void* __restrict__ w1_0, const void* __restrict__ b1_0,
    const void* __restrict__ w1_1, const void* __restrict__ b1_1,
    const void* __restrict__ w2_0, const void* __restrict__ b2_0,
    const void* __restrict__ w2_1, const void* __restrict__ b2_1,
    bf16* __restrict__ c2o, const int* __restrict__ flag)
{
  __shared__ SmConv12 sm;
  const int n  = blockIdx.z;
  const int og = blockIdx.y & 1;
  const int ty = blockIdx.y >> 1;                  // 0..15
  const int R0 = ty * 16, C0 = blockIdx.x * 16;
  const void* IN = n ? in1  : in0;                 // n=0 style/snet, 1 content/cnet
  const void* W1 = n ? w1_1 : w1_0;
  const void* B1 = n ? b1_1 : b1_0;
  const void* W2 = n ? w2_1 : w2_0;
  const void* B2 = n ? b2_1 : b2_0;
  bf16* OUT = c2o + (size_t)n * 2097152;
  if (flag[0]) conv12_impl<1>(IN, W1, B1, W2, B2, OUT, R0, C0, og, sm);
  else         conv12_impl<0>(IN, W1, B1, W2, B2, OUT, R0, C0, og, sm);
}

// ---------------------------------------------------------------------------
// conv3: 32->16 ch, 256^2 -> 128^2, s2 p1, NO relu, fp32 out [2][16][16384]
// og split (8 oc/thread) -> grid (64, 2, 2) = 256 blocks
// ---------------------------------------------------------------------------
struct SmConv3 { float wl[288][8]; float bl[8]; };

template<int F32>
__device__ __forceinline__ void conv3_impl(
    const bf16* __restrict__ IN, const void* __restrict__ W,
    const void* __restrict__ B, float* __restrict__ O, int og, SmConv3& sm)
{
  const int tid = threadIdx.x;
  for (int i = tid; i < 2304; i += 256) {          // 288*8
    int ocl = i & 7, kk = i >> 3;
    sm.wl[kk][ocl] = ldin<F32>(W, (size_t)(og * 8 + ocl) * 288 + kk);
  }
  if (tid < 8) sm.bl[tid] = ldin<F32>(B, og * 8 + tid);
  __syncthreads();
  const int s = blockIdx.x * 256 + tid;            // 0..16383
  const int oy = s >> 7, ox = s & 127;
  float acc[8];
  #pragma unroll
  for (int j = 0; j < 8; j++) acc[j] = sm.bl[j];
  for (int ic = 0; ic < 32; ic++) {
    const bf16* __restrict__ Ic = IN + (size_t)ic * 65536;
    #pragma unroll
    for (int ky = 0; ky < 3; ky++) {
      int iy = 2 * oy + ky - 1;
      bool oky = (unsigned)iy < 256u;
      #pragma unroll
      for (int kx = 0; kx < 3; kx++) {
        int ix = 2 * ox + kx - 1;
        float v = (oky && (unsigned)ix < 256u) ? b2f(Ic[(long)iy * 256 + ix]) : 0.f;
        const int kk = ic * 9 + ky * 3 + kx;
        float4 wA = *(const float4*)&sm.wl[kk][0];
        float4 wB = *(const float4*)&sm.wl[kk][4];
        acc[0] += wA.x * v; acc[1] += wA.y * v; acc[2] += wA.z * v; acc[3] += wA.w * v;
        acc[4] += wB.x * v; acc[5] += wB.y * v; acc[6] += wB.z * v; acc[7] += wB.w * v;
      }
    }
  }
  #pragma unroll
  for (int j = 0; j < 8; j++) O[(size_t)(og * 8 + j) * 16384 + s] = acc[j];
}

__global__ __launch_bounds__(256) void k_conv3(
    const bf16* __restrict__ in,
    const void* __restrict__ w0, const void* __restrict__ bi0,
    const void* __restrict__ w1, const void* __restrict__ bi1,
    float* __restrict__ out, const int* __restrict__ flag)
{
  __shared__ SmConv3 sm;
  const int n = blockIdx.z, og = blockIdx.y;
  const bf16* IN = in + (size_t)n * 32 * 65536;
  const void* W = n ? w1 : w0;
  const void* B = n ? bi1 : bi0;
  float* O = out + (size_t)n * 16 * 16384;
  if (flag[0]) conv3_impl<1>(IN, W, B, O, og, sm);
  else         conv3_impl<0>(IN, W, B, O, og, sm);
}

// ---------------------------------------------------------------------------
// gather + maxpool (fp32 scratch, dtype-independent)
// ---------------------------------------------------------------------------
__global__ __launch_bounds__(256) void k_pool(
    const float* __restrict__ feat, const int* __restrict__ fgs,
    const int* __restrict__ fgc, float* __restrict__ pooled)
{
  int t = blockIdx.x * 256 + threadIdx.x;   // 0..8191
  int n = t >> 12, rem = t & 4095;
  int c = rem >> 8, p = rem & 255;
  const int* __restrict__ m = n ? fgc : fgs;
  const float* __restrict__ F = feat + (size_t)n * 16 * 16384 + (size_t)c * 16384;
  float mx = -3.4e38f;
  #pragma unroll 4
  for (int j = 0; j < 32; j++) mx = fmaxf(mx, F[m[p * 32 + j]]);
  pooled[(size_t)n * 4096 + rem] = mx;
}

// ---------------------------------------------------------------------------
// FC: mats[n][i] = fcb[i] + sum_j pooled[n][j]*fcw[i][j]
// ---------------------------------------------------------------------------
template<int F32>
__device__ __forceinline__ void fc_impl(
    const float* __restrict__ P, const void* __restrict__ W,
    const void* __restrict__ B, float* __restrict__ dst, int i, float* red)
{
  const int tid = threadIdx.x;
  float p = 0.f;
  for (int j = tid; j < 4096; j += 256) p += P[j] * ldin<F32>(W, (size_t)i * 4096 + j);
  red[tid] = p;
  __syncthreads();
  for (int off = 128; off > 0; off >>= 1) {
    if (tid < off) red[tid] += red[tid + off];
    __syncthreads();
  }
  if (tid == 0) *dst = red[0] + ldin<F32>(B, i);
}

__global__ __launch_bounds__(256) void k_fc(
    const float* __restrict__ pooled,
    const void* __restrict__ w0, const void* __restrict__ bb0,
    const void* __restrict__ w1, const void* __restrict__ bb1,
    float* __restrict__ mats, const int* __restrict__ flag)
{
  __shared__ float red[256];
  const int n = blockIdx.z, i = blockIdx.x;
  const void* W = n ? w1 : w0;
  const void* B = n ? bb1 : bb0;
  const float* P = pooled + (size_t)n * 4096;
  float* dst = &mats[(size_t)n * 4096 + i];
  if (flag[0]) fc_impl<1>(P, W, B, dst, i, red);
  else         fc_impl<0>(P, W, B, dst, i, red);
}

// T = sMat @ cMat
__global__ __launch_bounds__(256) void k_tmat(
    const float* __restrict__ mats, float* __restrict__ T)
{
  int t = blockIdx.x * 256 + threadIdx.x;   // 0..4095
  int i = t >> 6, j = t & 63;
  const float* __restrict__ S = mats;
  const float* __restrict__ C = mats + 4096;
  float a = 0.f;
  #pragma unroll 8
  for (int k = 0; k < 64; k++) a += S[i * 64 + k] * C[k * 64 + j];
  T[t] = a;
}

// ---------------------------------------------------------------------------
// compress: ccf[o][s] = cb[o] + sum_c cw[o][c]*cF[c][s]  (fp32 out)
// ---------------------------------------------------------------------------
struct SmCompress { float wl[512][8]; float bl[8]; };

template<int F32>
__device__ __forceinline__ void compress_impl(
    const void* __restrict__ cF, const void* __restrict__ cw,
    const void* __restrict__ cb, float* __restrict__ ccf, int og, SmCompress& sm)
{
  const int tid = threadIdx.x;
  for (int i = tid; i < 4096; i += 256) {
    int ol = i & 7, c = i >> 3;
    sm.wl[c][ol] = ldin<F32>(cw, (size_t)(og * 8 + ol) * 512 + c);
  }
  if (tid < 8) sm.bl[tid] = ldin<F32>(cb, og * 8 + tid);
  __syncthreads();
  const int s = blockIdx.x * 256 + tid;
  float acc[8];
  #pragma unroll
  for (int j = 0; j < 8; j++) acc[j] = sm.bl[j];
  for (int c = 0; c < 512; c++) {
    float v = ldin<F32>(cF, (size_t)c * 16384 + s);
    float4 wA = *(const float4*)&sm.wl[c][0];
    float4 wB = *(const float4*)&sm.wl[c][4];
    acc[0] += wA.x * v; acc[1] += wA.y * v; acc[2] += wA.z * v; acc[3] += wA.w * v;
    acc[4] += wB.x * v; acc[5] += wB.y * v; acc[6] += wB.z * v; acc[7] += wB.w * v;
  }
  #pragma unroll
  for (int j = 0; j < 8; j++) ccf[(size_t)(og * 8 + j) * 16384 + s] = acc[j];
}

__global__ __launch_bounds__(256) void k_compress(
    const void* __restrict__ cF, const void* __restrict__ cw,
    const void* __restrict__ cb, float* __restrict__ ccf,
    const int* __restrict__ flag)
{
  __shared__ SmCompress sm;
  const int og = blockIdx.y;
  if (flag[0]) compress_impl<1>(cF, cw, cb, ccf, og, sm);
  else         compress_impl<0>(cF, cw, cb, ccf, og, sm);
}

__global__ __launch_bounds__(256) void k_mean(
    const float* __restrict__ ccf, float* __restrict__ mean)
{
  const int o = blockIdx.x;
  const int tid = threadIdx.x;
  __shared__ float red[256];
  const float* __restrict__ R = ccf + (size_t)o * 16384;
  float p = 0.f;
  for (int s = tid; s < 16384; s += 256) p += R[s];
  red[tid] = p;
  __syncthreads();
  for (int off = 128; off > 0; off >>= 1) {
    if (tid < off) red[tid] += red[tid + off];
    __syncthreads();
  }
  if (tid == 0) mean[o] = red[0] * (1.f / 16384.f);
}

__global__ __launch_bounds__(256) void k_scatter(
    const int* __restrict__ fgc, int* __restrict__ maskf)
{
  int t = blockIdx.x * 256 + threadIdx.x;   // 0..8191
  maskf[fgc[t]] = 1;
}

// ---------------------------------------------------------------------------
// transform -> tf bf16 (scratch-only, dtype-independent)
// ---------------------------------------------------------------------------
__global__ __launch_bounds__(256) void k_transform(
    const float* __restrict__ ccf, const float* __restrict__ Tm,
    const float* __restrict__ mean, const int* __restrict__ maskf,
    bf16* __restrict__ tf)
{
  const int og = blockIdx.y;
  __shared__ __align__(16) float Tl[16][64];
  __shared__ float ml[64];
  const int tid = threadIdx.x;
  for (int i = tid; i < 1024; i += 256) {
    int ol = i >> 6, op = i & 63;
    Tl[ol][op] = Tm[(size_t)(og * 16 + ol) * 64 + op];
  }
  if (tid < 64) ml[tid] = mean[tid];
  __syncthreads();
  const int s = blockIdx.x * 256 + tid;
  const bool msk = maskf[s] != 0;
  float col[64];
  #pragma unroll
  for (int op = 0; op < 64; op++) col[op] = ccf[(size_t)op * 16384 + s] - ml[op];
  #pragma unroll
  for (int ol = 0; ol < 16; ol++) {
    float a = 0.f;
    #pragma unroll
    for (int op4 = 0; op4 < 16; op4++) {
      float4 t4 = *(const float4*)&Tl[ol][op4 * 4];
      a += t4.x * col[op4*4+0] + t4.y * col[op4*4+1]
         + t4.z * col[op4*4+2] + t4.w * col[op4*4+3];
    }
    float un = ccf[(size_t)(og * 16 + ol) * 16384 + s] - ml[og * 16 + ol];
    tf[(size_t)(og * 16 + ol) * 16384 + s] = f2b(msk ? a : un);
  }
}

// ---------------------------------------------------------------------------
// unzip: out[u][s] = ub[u] + sum_o uw[u][o]*tf[o][s]  -> out dtype per flag
// ---------------------------------------------------------------------------
struct SmUnzip { float wl[64][32]; float bl[32]; };

template<int F32>
__device__ __forceinline__ void unzip_impl(
    const bf16* __restrict__ tf, const void* __restrict__ uw,
    const void* __restrict__ ub, void* __restrict__ outp, int ug, SmUnzip& sm)
{
  const int tid = threadIdx.x;
  for (int i = tid; i < 2048; i += 256) {
    int ul = i & 31, o = i >> 5;
    sm.wl[o][ul] = ldin<F32>(uw, (size_t)(ug * 32 + ul) * 64 + o);
  }
  if (tid < 32) sm.bl[tid] = ldin<F32>(ub, ug * 32 + tid);
  __syncthreads();
  const int s = blockIdx.x * 256 + tid;
  float acc[32];
  #pragma unroll
  for (int j = 0; j < 32; j++) acc[j] = sm.bl[j];
  #pragma unroll 4
  for (int o = 0; o < 64; o++) {
    float v = b2f(tf[(size_t)o * 16384 + s]);
    #pragma unroll
    for (int j4 = 0; j4 < 8; j4++) {
      float4 w4 = *(const float4*)&sm.wl[o][j4 * 4];
      acc[j4*4+0] += w4.x * v; acc[j4*4+1] += w4.y * v;
      acc[j4*4+2] += w4.z * v; acc[j4*4+3] += w4.w * v;
    }
  }
  #pragma unroll
  for (int j = 0; j < 32; j++) {
    size_t idx = (size_t)(ug * 32 + j) * 16384 + s;
    if (F32) ((float*)outp)[idx] = acc[j];
    else     ((bf16*)outp)[idx]  = f2b(acc[j]);
  }
}

__global__ __launch_bounds__(256) void k_unzip(
    const bf16* __restrict__ tf, const void* __restrict__ uw,
    const void* __restrict__ ub, void* __restrict__ outp,
    const int* __restrict__ flag)
{
  __shared__ SmUnzip sm;
  const int ug = blockIdx.y;
  if (flag[0]) unzip_impl<1>(tf, uw, ub, outp, ug, sm);
  else         unzip_impl<0>(tf, uw, ub, outp, ug, sm);
}

// ---------------------------------------------------------------------------
extern "C" void kernel_launch(void* const* d_in, const int* in_sizes, int n_in,
                              void* d_out, int out_size, void* d_ws, size_t ws_size,
                              hipStream_t stream)
{
  const void* cF      = d_in[0];
  // d_in[1] = sF (unused by reference)
  const void* content = d_in[2];
  const void* style   = d_in[3];
  const void* s_c1w = d_in[4];  const void* s_c1b = d_in[5];
  const void* s_c2w = d_in[6];  const void* s_c2b = d_in[7];
  const void* s_c3w = d_in[8];  const void* s_c3b = d_in[9];
  const void* s_fcw = d_in[10]; const void* s_fcb = d_in[11];
  const void* c_c1w = d_in[12]; const void* c_c1b = d_in[13];
  const void* c_c2w = d_in[14]; const void* c_c2b = d_in[15];
  const void* c_c3w = d_in[16]; const void* c_c3b = d_in[17];
  const void* c_fcw = d_in[18]; const void* c_fcb = d_in[19];
  const void* cw = d_in[20];    const void* cb = d_in[21];
  const void* uw = d_in[22];    const void* ub = d_in[23];
  const int* fgc = (const int*)d_in[24];
  const int* fgs = (const int*)d_in[25];
  (void)in_sizes; (void)n_in; (void)out_size; (void)ws_size;

  // scratch inside d_out (14.83 MB; d_out >= 16.77 MB); fully rewritten by
  // the final k_unzip which reads nothing from d_out.
  char* ob = (char*)d_out;
  bf16*  c2o    = (bf16*)(ob + 0);           // [2][32][65536] bf16  8,388,608 B
  float* c3o    = (float*)(ob + 8388608);    // [2][16][16384] f32   2,097,152 B
  float* ccf    = (float*)(ob + 10485760);   // [64][16384]  f32     4,194,304 B
  float* pooled = (float*)(ob + 14680064);   // [2][4096]               32,768 B
  float* mats   = (float*)(ob + 14712832);   // [2][4096]               32,768 B
  float* T      = (float*)(ob + 14745600);   // [64][64]                16,384 B
  float* mean   = (float*)(ob + 14761984);   // [64]+pad                 1,024 B
  int*   maskf  = (int*)(ob + 14763008);     // [16384]                 65,536 B
  int*   flag   = (int*)(ob + 14828544);     // dtype flag                  16 B

  bf16* tf = (bf16*)d_ws;                    // [64][16384] bf16, 2,097,152 B

  k_detect<<<1, 64, 0, stream>>>((const unsigned short*)cF, flag);
  (void)hipMemsetAsync(maskf, 0, 16384 * sizeof(int), stream);
  k_scatter<<<32, 256, 0, stream>>>(fgc, maskf);

  // fused conv1+conv2: 1024 blocks
  k_conv12<<<dim3(16, 32, 2), 256, 0, stream>>>(
      style, content, s_c1w, s_c1b, c_c1w, c_c1b,
      s_c2w, s_c2b, c_c2w, c_c2b, c2o, flag);

  k_conv3<<<dim3(64, 2, 2), 256, 0, stream>>>(c2o, s_c3w, s_c3b, c_c3w, c_c3b, c3o, flag);
  k_pool<<<32, 256, 0, stream>>>(c3o, fgs, fgc, pooled);
  k_fc<<<dim3(4096, 1, 2), 256, 0, stream>>>(pooled, s_fcw, s_fcb, c_fcw, c_fcb, mats, flag);
  k_tmat<<<16, 256, 0, stream>>>(mats, T);

  k_compress<<<dim3(64, 8), 256, 0, stream>>>(cF, cw, cb, ccf, flag);
  k_mean<<<64, 256, 0, stream>>>(ccf, mean);
  k_transform<<<dim3(64, 4), 256, 0, stream>>>(ccf, T, mean, maskf, tf);
  k_unzip<<<dim3(64, 16), 256, 0, stream>>>(tf, uw, ub, d_out, flag);
}